// Round 13
// baseline (59.590 us; speedup 1.0000x reference)
//
#include <hip/hip_runtime.h>
#include <math.h>

#define N1 1024
#define DPROJ 1024
#define M_NODES 4368
#define N2 (N1 + M_NODES)      // 5392
#define N2P 5504               // padded to 43*128 for the GEMM
#define L_LEAVES 4096
#define INV_T (1.0f / 0.07f)
#define NBX 43                 // N2P / BN

typedef __bf16 bf16;
typedef __bf16 bf16x4v __attribute__((ext_vector_type(4)));
typedef __bf16 bf16x8 __attribute__((ext_vector_type(8)));
typedef float f32x4 __attribute__((ext_vector_type(4)));

// ---------------------------------------------------------------------------
// Kernel A: fused normalize + bf16 cast. kn[row] = row/max(||row||,1e-12);
// rows >= N2 zero-filled (GEMM padding). Block 0 also zeroes d_out.
// ---------------------------------------------------------------------------
__global__ __launch_bounds__(256) void normalize_kernel(
    const float* __restrict__ q, const float* __restrict__ vc,
    bf16* __restrict__ kn, float* __restrict__ out) {
  const int row = blockIdx.x;
  if (row == 0 && threadIdx.x == 0) { out[0] = 0.f; out[1] = 0.f; }
  bf16x4v* dst = (bf16x4v*)(kn + (size_t)row * DPROJ);
  if (row >= N2) {
    bf16x4v z = {(bf16)0.f, (bf16)0.f, (bf16)0.f, (bf16)0.f};
    dst[threadIdx.x] = z;
    return;
  }
  const float* src = (row < N1) ? q + (size_t)row * DPROJ
                                : vc + (size_t)(row - N1) * DPROJ;
  float4 v = ((const float4*)src)[threadIdx.x];
  float s = v.x * v.x + v.y * v.y + v.z * v.z + v.w * v.w;
  for (int off = 32; off > 0; off >>= 1) s += __shfl_down(s, off);
  __shared__ float wsum[4];
  const int lane = threadIdx.x & 63, wid = threadIdx.x >> 6;
  if (lane == 0) wsum[wid] = s;
  __syncthreads();
  const float tot = wsum[0] + wsum[1] + wsum[2] + wsum[3];
  const float inv = 1.0f / fmaxf(sqrtf(tot), 1e-12f);
  bf16x4v o = {(bf16)(v.x * inv), (bf16)(v.y * inv), (bf16)(v.z * inv),
               (bf16)(v.w * inv)};
  dst[threadIdx.x] = o;
}

// ---------------------------------------------------------------------------
// Kernel B: fused GEMM + loss partials.
// R13 change: 128x128 block tile (was 64x128), BK=64, 4 waves as 2x2 with
// SQUARE 64x64 wave tiles -> LDS traffic per output 0.67x; 344 blocks
// (= 8 XCDs x 43, exactly divisible -> clean chunked swizzle: each XCD a
// ~5.4-wide bx band x all by: B 1.4MB + A 2MB = 3.4MB, L2-resident);
// 71 KB LDS -> 2 blocks/CU resident -> whole grid runs concurrently;
// barrier-iterations per CU drop 43 -> 32 with 2x work per iteration.
// Sync = R12's proven scheme: 2 bufs, STAGE(it+1) first, counted vmcnt(8)
// (own 8 staging loads of tile it), raw s_barriers. 128B-row XOR swizzle
// (R12): physical 16B-slot = logical ^ (row&7), pre-swizzled global src.
// (R3's 128x128 failure was broken sync + 1 block/CU, not the tile size.)
// ---------------------------------------------------------------------------
#define BM 128
#define BN 128
#define BK 64
#define NT (DPROJ / BK)
#define NBY 8                  // N1 / BM

__device__ __forceinline__ void gload16(const bf16* g, bf16* l) {
  __builtin_amdgcn_global_load_lds(
      (const __attribute__((address_space(1))) void*)g,
      (__attribute__((address_space(3))) void*)l, 16, 0, 0);
}

__global__ __launch_bounds__(256, 2) void gemm_loss_kernel(
    const bf16* __restrict__ kn, const int* __restrict__ labels,
    float* __restrict__ partials) {
  __shared__ bf16 As[2][BM][BK];         // 32 KB
  __shared__ bf16 Bs[2][BN][BK];         // 32 KB
  __shared__ int lab_r[BM];              // 512 B
  __shared__ int lab_c[BN];              // 512 B
  __shared__ float blk_part[BM][2][6];   // 6 KB
  // Chunked bijective XCD swizzle (344 = 8 x 43): xcd = wg&7 owns vids
  // [43*xcd, 43*xcd+43); vid -> (bx = vid>>3 band, by = vid&7).
  const int wg = blockIdx.y * NBX + blockIdx.x;
  const int vid = (wg & 7) * 43 + (wg >> 3);
  const int bx = vid >> 3;          // 0..42
  const int by = vid & 7;           // 0..7
  const int j0 = bx * BN;
  const int i0 = by * BM;
  const int t = threadIdx.x;
  const int lane = t & 63, w = t >> 6;
  const int wm = w >> 1, wn = w & 1;   // wave grid 2x2, wave tile 64x64

  if (t < BM) lab_r[t] = labels[i0 + t];
  if (t < BN && j0 + t < N1) lab_c[t] = labels[j0 + t];

  f32x4 acc[4][4] = {};

  // Staging: one gload16 = 8 rows x 128 B. lane -> row = lane>>3, physical
  // 16B-slot = lane&7; global slot pre-swizzled by row&7:
  // s_src = (lane&7) ^ ((lane>>3)&7).
  const int rik = lane >> 3;
  const int kswz = ((lane & 7) ^ ((lane >> 3) & 7)) * 8;
  // Wave w stages A rows [32w, 32w+32) and B rows [32w, 32w+32) (4+4 gloads).
  const bf16* gA0 = kn + (size_t)(i0 + w * 32 + rik) * DPROJ + kswz;
  const bf16* gA1 = gA0 + (size_t)8 * DPROJ;
  const bf16* gA2 = gA0 + (size_t)16 * DPROJ;
  const bf16* gA3 = gA0 + (size_t)24 * DPROJ;
  const bf16* gB0 = kn + (size_t)(j0 + w * 32 + rik) * DPROJ + kswz;
  const bf16* gB1 = gB0 + (size_t)8 * DPROJ;
  const bf16* gB2 = gB0 + (size_t)16 * DPROJ;
  const bf16* gB3 = gB0 + (size_t)24 * DPROJ;

  // Fragment reads: row = base + (lane&15) + 16m, bases mult of 64 ->
  // row&7 = lane&7. k-step kk in {0,1}, group g = lane>>4: logical slot
  // kk*4+g, physical = (kk*4+g) ^ (lane&7); elem offset = slot*8.
  const int ar = wm * 64 + (lane & 15);
  const int br = wn * 64 + (lane & 15);
  const int l7 = lane & 7;
  const int g4 = lane >> 4;
  const int kf0 = (g4 ^ l7) * 8;          // kk = 0
  const int kf1 = ((4 + g4) ^ l7) * 8;    // kk = 1

#define STAGE(buf, k0)                             \
  do {                                             \
    gload16(gA0 + (k0), &As[buf][w * 32][0]);      \
    gload16(gA1 + (k0), &As[buf][w * 32 + 8][0]);  \
    gload16(gA2 + (k0), &As[buf][w * 32 + 16][0]); \
    gload16(gA3 + (k0), &As[buf][w * 32 + 24][0]); \
    gload16(gB0 + (k0), &Bs[buf][w * 32][0]);      \
    gload16(gB1 + (k0), &Bs[buf][w * 32 + 8][0]);  \
    gload16(gB2 + (k0), &Bs[buf][w * 32 + 16][0]); \
    gload16(gB3 + (k0), &Bs[buf][w * 32 + 24][0]); \
  } while (0)

  // Prologue: tile 0 into buf 0; full drain (labels visible too).
  STAGE(0, 0);
  __syncthreads();

#pragma unroll 2
  for (int it = 0; it < NT; ++it) {
    const int cur = it & 1;
    if (it + 1 < NT) {
      STAGE(cur ^ 1, (it + 1) * BK);
      asm volatile("s_waitcnt vmcnt(8)" ::: "memory");  // oldest 8 = tile it
    } else {
      asm volatile("s_waitcnt vmcnt(0)" ::: "memory");
    }
    __builtin_amdgcn_s_barrier();   // all waves' tile-it loads complete

    bf16x8 a0[4], a1[4], b0[4], b1[4];
#pragma unroll
    for (int m = 0; m < 4; ++m) {
      a0[m] = *(const bf16x8*)&As[cur][ar + m * 16][kf0];
      a1[m] = *(const bf16x8*)&As[cur][ar + m * 16][kf1];
    }
#pragma unroll
    for (int n = 0; n < 4; ++n) {
      b0[n] = *(const bf16x8*)&Bs[cur][br + n * 16][kf0];
      b1[n] = *(const bf16x8*)&Bs[cur][br + n * 16][kf1];
    }
#pragma unroll
    for (int m = 0; m < 4; ++m)
#pragma unroll
      for (int n = 0; n < 4; ++n) {
        acc[m][n] = __builtin_amdgcn_mfma_f32_16x16x32_bf16(
            a0[m], b0[n], acc[m][n], 0, 0, 0);
        acc[m][n] = __builtin_amdgcn_mfma_f32_16x16x32_bf16(
            a1[m], b1[n], acc[m][n], 0, 0, 0);
      }

    __builtin_amdgcn_s_barrier();   // reads of buf[cur] done -> reusable
  }

  // Fused epilogue. C/D layout: col=lane&15, row=(lane>>4)*4+j [m89].
  const int g = lane >> 4;
  const int p = lane & 15;
#pragma unroll
  for (int m = 0; m < 4; ++m) {
#pragma unroll
    for (int j = 0; j < 4; ++j) {
      const int rloc = wm * 64 + m * 16 + g * 4 + j;
      const int lab = lab_r[rloc];
      const int a2 = lab >> 4, a1 = lab >> 8;
      float ps0 = 0, ps1 = 0, ps2 = 0, ns0 = 0, ns1 = 0, ns2 = 0;
#pragma unroll
      for (int n = 0; n < 4; ++n) {
        const int cloc = wn * 64 + n * 16 + p;
        const int gc = j0 + cloc;
        if (gc < N2) {
          const int nid = (gc < N1) ? lab_c[cloc] : (gc - N1);
          const bool isLeaf = nid < L_LEAVES;
          const bool isD2 = (nid >= L_LEAVES) && (nid < L_LEAVES + 256);
          const bool eq = (nid == lab);
          const bool inS2 =
              (nid == L_LEAVES + a2) || (isLeaf && ((nid >> 4) == a2));
          const bool inS1 = (nid == L_LEAVES + 256 + a1) ||
                            (isD2 && (((nid - L_LEAVES) >> 4) == a1)) ||
                            (isLeaf && ((nid >> 8) == a1));
          const float v = acc[m][n][j] * INV_T;
          const float e = __expf(v);
          if (eq) ps2 += v; else ns2 += e;
          if (inS2) { if (!eq) ps1 += v; } else ns1 += e;
          if (inS1) { if (!inS2) ps0 += v; } else ns0 += e;
        }
      }
#pragma unroll
      for (int msk = 1; msk < 16; msk <<= 1) {
        ps0 += __shfl_xor(ps0, msk);
        ps1 += __shfl_xor(ps1, msk);
        ps2 += __shfl_xor(ps2, msk);
        ns0 += __shfl_xor(ns0, msk);
        ns1 += __shfl_xor(ns1, msk);
        ns2 += __shfl_xor(ns2, msk);
      }
      if (p == 0) {
        float* d = &blk_part[rloc][wn][0];
        d[0] = ps0; d[1] = ps1; d[2] = ps2;
        d[3] = ns0; d[4] = ns1; d[5] = ns2;
      }
    }
  }
  __syncthreads();
  for (int idx = t; idx < BM * 6; idx += 256) {
    const int r = idx / 6, k = idx % 6;
    const float val = blk_part[r][0][k] + blk_part[r][1][k];
    partials[((size_t)(i0 + r) * NBX + bx) * 6 + k] = val;
  }
}

// ---------------------------------------------------------------------------
// Kernel C: finalize. LDS label histogram, sum 43 slices/row, CE with
// analytic counts: |eq|=hist[lab]+1; |S2|=hist2+17; |S1|=hist1+273.
// Masked entries contribute exp(0)=1 -> +|set| in the LSE.
// ---------------------------------------------------------------------------
__global__ __launch_bounds__(256) void finalize_kernel(
    const float* __restrict__ partials, const int* __restrict__ labels,
    const float* __restrict__ depth, float* __restrict__ out) {
  __shared__ int hist_s[M_NODES];   // 17.4 KB
  const int t = threadIdx.x;
  for (int i = t; i < M_NODES; i += 256) hist_s[i] = 0;
  __syncthreads();
  for (int i = t; i < N1; i += 256) {
    const int lb = labels[i];
    atomicAdd(&hist_s[lb], 1);
    atomicAdd(&hist_s[L_LEAVES + (lb >> 4)], 1);
    atomicAdd(&hist_s[L_LEAVES + 256 + (lb >> 8)], 1);
  }
  __syncthreads();

  const int row = blockIdx.x * 256 + t;
  const int lab = labels[row];
  const int a2 = lab >> 4, a1 = lab >> 8;
  const int cEq = hist_s[lab] + 1;
  const int cS2 = hist_s[L_LEAVES + a2] + 17;
  const int cS1 = hist_s[L_LEAVES + 256 + a1] + 273;
  float ps0 = 0, ps1 = 0, ps2 = 0, ns0 = 0, ns1 = 0, ns2 = 0;
  const float* pp = partials + (size_t)row * NBX * 6;
  for (int b = 0; b < NBX; ++b) {
    ps0 += pp[b * 6 + 0];
    ps1 += pp[b * 6 + 1];
    ps2 += pp[b * 6 + 2];
    ns0 += pp[b * 6 + 3];
    ns1 += pp[b * 6 + 4];
    ns2 += pp[b * 6 + 5];
  }
  float ce = 0.f;
  {
    float pl = ps2 / fmaxf((float)cEq, 1e-6f);
    ce += logf(ns2 + (float)cEq + __expf(pl)) - pl;
  }
  {
    float pl = ps1 / fmaxf((float)(cS2 - cEq), 1e-6f);
    ce += logf(ns1 + (float)cS2 + __expf(pl)) - pl;
  }
  {
    float pl = ps0 / fmaxf((float)(cS1 - cS2), 1e-6f);
    ce += logf(ns0 + (float)cS1 + __expf(pl)) - pl;
  }
  float contrib = ce / depth[lab] * (3.0f / (float)N1);
  for (int off = 32; off > 0; off >>= 1) contrib += __shfl_down(contrib, off);
  __shared__ float wsum[4];
  const int lane = t & 63, wid = t >> 6;
  if (lane == 0) wsum[wid] = contrib;
  __syncthreads();
  if (t == 0) {
    const float tot = wsum[0] + wsum[1] + wsum[2] + wsum[3];
    atomicAdd(&out[0], tot);
    atomicAdd(&out[1], tot);
  }
}

// ---------------------------------------------------------------------------
extern "C" void kernel_launch(void* const* d_in, const int* in_sizes, int n_in,
                              void* d_out, int out_size, void* d_ws,
                              size_t ws_size, hipStream_t stream) {
  const float* q = (const float*)d_in[0];
  const float* vc = (const float*)d_in[1];
  const int* labels = (const int*)d_in[2];
  const float* depth = (const float*)d_in[6];
  float* out = (float*)d_out;

  bf16* kn = (bf16*)d_ws;  // N2P*DPROJ bf16 = 11.27 MB
  float* partials = (float*)((char*)d_ws + (size_t)N2P * DPROJ * sizeof(bf16));
  // partials: N1 * NBX * 6 floats (~1.06 MB), fully written -> no memset

  normalize_kernel<<<N2P, 256, 0, stream>>>(q, vc, kn, out);

  dim3 grid(NBX, NBY);
  gemm_loss_kernel<<<grid, 256, 0, stream>>>(kn, labels, partials);

  finalize_kernel<<<4, 256, 0, stream>>>(partials, labels, depth, out);
}

// Round 14
// 45.687 us; speedup vs baseline: 1.3043x; 1.3043x over previous
//
#include <hip/hip_runtime.h>
#include <math.h>

#define N1 1024
#define DPROJ 1024
#define M_NODES 4368
#define N2 (N1 + M_NODES)      // 5392
#define N2P 5504               // padded to 43*128 for the GEMM
#define L_LEAVES 4096
#define INV_T (1.0f / 0.07f)
#define NBX 43                 // N2P / BN

typedef float f32x4 __attribute__((ext_vector_type(4)));

// ---------------------------------------------------------------------------
// Kernel A: fused normalize + fp8(e4m3) cast. kn[row] = row/max(||row||,1e-12)
// quantized to OCP e4m3; rows >= N2 zero-filled. Block 0 also zeroes d_out.
// Unit-norm elements (~±0.03..0.15) sit comfortably in e4m3 range.
// ---------------------------------------------------------------------------
__global__ __launch_bounds__(256) void normalize_kernel(
    const float* __restrict__ q, const float* __restrict__ vc,
    unsigned char* __restrict__ kn, float* __restrict__ out) {
  const int row = blockIdx.x;
  if (row == 0 && threadIdx.x == 0) { out[0] = 0.f; out[1] = 0.f; }
  int* dst = (int*)(kn + (size_t)row * DPROJ);
  if (row >= N2) {
    dst[threadIdx.x] = 0;
    return;
  }
  const float* src = (row < N1) ? q + (size_t)row * DPROJ
                                : vc + (size_t)(row - N1) * DPROJ;
  float4 v = ((const float4*)src)[threadIdx.x];
  float s = v.x * v.x + v.y * v.y + v.z * v.z + v.w * v.w;
  for (int off = 32; off > 0; off >>= 1) s += __shfl_down(s, off);
  __shared__ float wsum[4];
  const int lane = threadIdx.x & 63, wid = threadIdx.x >> 6;
  if (lane == 0) wsum[wid] = s;
  __syncthreads();
  const float tot = wsum[0] + wsum[1] + wsum[2] + wsum[3];
  const float inv = 1.0f / fmaxf(sqrtf(tot), 1e-12f);
  int p = __builtin_amdgcn_cvt_pk_fp8_f32(v.x * inv, v.y * inv, 0, false);
  p = __builtin_amdgcn_cvt_pk_fp8_f32(v.z * inv, v.w * inv, p, true);
  dst[threadIdx.x] = p;
}

// ---------------------------------------------------------------------------
// Kernel B: fused GEMM + loss partials — R12 structure, fp8 data path.
// 64x128 tile, BK=64 (= 64 B rows), 2x2 waves of 32x64, 688 blocks,
// 2 LDS buffers, STAGE(it+1)-first, counted vmcnt(3) (own 3 staging loads
// of tile it), raw s_barriers, chunked XCD swizzle. LDS 27.75 KB ->
// 5 blocks/CU (20 waves/CU) — fp8 halves staged bytes, LDS reads (b64),
// and LDS footprint; MFMA count unchanged (K=32 fp8 = bf16 K).
// Swizzle (64B rows, 16B gload granules): physical 8B-subslot =
// logical ^ (2*((row>>1)&3)) — even-XOR keeps 16B granules intact
// (granule m_phys = m ^ ((row>>1)&3), bit0 preserved); reads land 2-way
// max (free, m136). Staging pre-swizzles global granule by the same
// involution: (lane&3) ^ ((lane>>3)&3), within-row -> coalescing intact.
// ---------------------------------------------------------------------------
#define BM 64
#define BN 128
#define BK 64
#define NT (DPROJ / BK)

__device__ __forceinline__ void gload16(const unsigned char* g,
                                        unsigned char* l) {
  __builtin_amdgcn_global_load_lds(
      (const __attribute__((address_space(1))) void*)g,
      (__attribute__((address_space(3))) void*)l, 16, 0, 0);
}

__global__ __launch_bounds__(256, 5) void gemm_loss_kernel(
    const unsigned char* __restrict__ kn, const int* __restrict__ labels,
    float* __restrict__ partials) {
  __shared__ unsigned char As[2][BM][BK];   // 8 KB
  __shared__ unsigned char Bs[2][BN][BK];   // 16 KB
  __shared__ int lab_r[BM];                 // 256 B
  __shared__ int lab_c[BN];                 // 512 B
  __shared__ float blk_part[BM][2][6];      // 3 KB
  // Chunked bijective XCD swizzle (688 = 8 x 86), y-fastest chunks.
  const int wg = blockIdx.y * NBX + blockIdx.x;
  const int vid = (wg & 7) * 86 + (wg >> 3);
  const int bx = vid >> 4;          // 0..42
  const int by = vid & 15;          // 0..15
  const int j0 = bx * BN;
  const int i0 = by * BM;
  const int t = threadIdx.x;
  const int lane = t & 63, w = t >> 6;
  const int wm = w >> 1, wn = w & 1;   // wave grid 2x2, wave tile 32x64

  if (t < BM) lab_r[t] = labels[i0 + t];
  if (t < BN && j0 + t < N1) lab_c[t] = labels[j0 + t];

  f32x4 acc[2][4] = {};

  // Staging: one gload16 = 16 rows x 64 B (4 lanes/row). lane -> row =
  // lane>>2, granule = lane&3; global granule pre-swizzled by (row>>1)&3:
  // (lane&3) ^ ((lane>>3)&3).
  const int rik = lane >> 2;
  const int gswz = ((lane & 3) ^ ((lane >> 3) & 3)) * 16;
  // Wave w: A rows [16w,16w+16) (1 gload); B rows [16w..), [64+16w..) (2).
  const unsigned char* gA = kn + (size_t)(i0 + w * 16 + rik) * DPROJ + gswz;
  const unsigned char* gB0 = kn + (size_t)(j0 + w * 16 + rik) * DPROJ + gswz;
  const unsigned char* gB1 = gB0 + (size_t)64 * DPROJ;

  // Fragment reads (8 B per k-step): row = base + (lane&15) (bases mult of
  // 32 -> (row>>1)&3 = (lane>>1)&3); logical 8B-subslot s = kk*4 + g
  // (g = lane>>4), physical = s ^ (2*((lane>>1)&3)); byte offset = *8.
  const int ar = wm * 32 + (lane & 15);
  const int br = wn * 64 + (lane & 15);
  const int x2 = 2 * ((lane >> 1) & 3);
  const int g4 = lane >> 4;
  const int kf0 = (g4 ^ x2) * 8;          // kk = 0
  const int kf1 = ((4 + g4) ^ x2) * 8;    // kk = 1

#define STAGE(buf, k0)                            \
  do {                                            \
    gload16(gA + (k0), &As[buf][w * 16][0]);      \
    gload16(gB0 + (k0), &Bs[buf][w * 16][0]);     \
    gload16(gB1 + (k0), &Bs[buf][w * 16 + 64][0]);\
  } while (0)

  // Prologue: tile 0 into buf 0; full drain (labels visible too).
  STAGE(0, 0);
  __syncthreads();

#pragma unroll 2
  for (int it = 0; it < NT; ++it) {
    const int cur = it & 1;
    if (it + 1 < NT) {
      STAGE(cur ^ 1, (it + 1) * BK);
      asm volatile("s_waitcnt vmcnt(3)" ::: "memory");  // oldest 3 = tile it
    } else {
      asm volatile("s_waitcnt vmcnt(0)" ::: "memory");
    }
    __builtin_amdgcn_s_barrier();   // all waves' tile-it loads complete

    long a0[2], a1[2], b0[4], b1[4];
#pragma unroll
    for (int m = 0; m < 2; ++m) {
      a0[m] = *(const long*)&As[cur][ar + m * 16][kf0];
      a1[m] = *(const long*)&As[cur][ar + m * 16][kf1];
    }
#pragma unroll
    for (int n = 0; n < 4; ++n) {
      b0[n] = *(const long*)&Bs[cur][br + n * 16][kf0];
      b1[n] = *(const long*)&Bs[cur][br + n * 16][kf1];
    }
#pragma unroll
    for (int m = 0; m < 2; ++m)
#pragma unroll
      for (int n = 0; n < 4; ++n) {
        acc[m][n] = __builtin_amdgcn_mfma_f32_16x16x32_fp8_fp8(
            a0[m], b0[n], acc[m][n], 0, 0, 0);
        acc[m][n] = __builtin_amdgcn_mfma_f32_16x16x32_fp8_fp8(
            a1[m], b1[n], acc[m][n], 0, 0, 0);
      }

    __builtin_amdgcn_s_barrier();   // reads of buf[cur] done -> reusable
  }

  // Fused epilogue. C/D layout: col=lane&15, row=(lane>>4)*4+j [m89,
  // dtype-independent per m121-m128].
  const int g = lane >> 4;
  const int p = lane & 15;
#pragma unroll
  for (int m = 0; m < 2; ++m) {
#pragma unroll
    for (int j = 0; j < 4; ++j) {
      const int rloc = wm * 32 + m * 16 + g * 4 + j;
      const int lab = lab_r[rloc];
      const int a2 = lab >> 4, a1 = lab >> 8;
      float ps0 = 0, ps1 = 0, ps2 = 0, ns0 = 0, ns1 = 0, ns2 = 0;
#pragma unroll
      for (int n = 0; n < 4; ++n) {
        const int cloc = wn * 64 + n * 16 + p;
        const int gc = j0 + cloc;
        if (gc < N2) {
          const int nid = (gc < N1) ? lab_c[cloc] : (gc - N1);
          const bool isLeaf = nid < L_LEAVES;
          const bool isD2 = (nid >= L_LEAVES) && (nid < L_LEAVES + 256);
          const bool eq = (nid == lab);
          const bool inS2 =
              (nid == L_LEAVES + a2) || (isLeaf && ((nid >> 4) == a2));
          const bool inS1 = (nid == L_LEAVES + 256 + a1) ||
                            (isD2 && (((nid - L_LEAVES) >> 4) == a1)) ||
                            (isLeaf && ((nid >> 8) == a1));
          const float v = acc[m][n][j] * INV_T;
          const float e = __expf(v);
          if (eq) ps2 += v; else ns2 += e;
          if (inS2) { if (!eq) ps1 += v; } else ns1 += e;
          if (inS1) { if (!inS2) ps0 += v; } else ns0 += e;
        }
      }
#pragma unroll
      for (int msk = 1; msk < 16; msk <<= 1) {
        ps0 += __shfl_xor(ps0, msk);
        ps1 += __shfl_xor(ps1, msk);
        ps2 += __shfl_xor(ps2, msk);
        ns0 += __shfl_xor(ns0, msk);
        ns1 += __shfl_xor(ns1, msk);
        ns2 += __shfl_xor(ns2, msk);
      }
      if (p == 0) {
        float* d = &blk_part[rloc][wn][0];
        d[0] = ps0; d[1] = ps1; d[2] = ps2;
        d[3] = ns0; d[4] = ns1; d[5] = ns2;
      }
    }
  }
  __syncthreads();
  for (int idx = t; idx < BM * 6; idx += 256) {
    const int r = idx / 6, k = idx % 6;
    const float val = blk_part[r][0][k] + blk_part[r][1][k];
    partials[((size_t)(i0 + r) * NBX + bx) * 6 + k] = val;
  }
}

// ---------------------------------------------------------------------------
// Kernel C: finalize. LDS label histogram, sum 43 slices/row, CE with
// analytic counts: |eq|=hist[lab]+1; |S2|=hist2+17; |S1|=hist1+273.
// Masked entries contribute exp(0)=1 -> +|set| in the LSE.
// ---------------------------------------------------------------------------
__global__ __launch_bounds__(256) void finalize_kernel(
    const float* __restrict__ partials, const int* __restrict__ labels,
    const float* __restrict__ depth, float* __restrict__ out) {
  __shared__ int hist_s[M_NODES];   // 17.4 KB
  const int t = threadIdx.x;
  for (int i = t; i < M_NODES; i += 256) hist_s[i] = 0;
  __syncthreads();
  for (int i = t; i < N1; i += 256) {
    const int lb = labels[i];
    atomicAdd(&hist_s[lb], 1);
    atomicAdd(&hist_s[L_LEAVES + (lb >> 4)], 1);
    atomicAdd(&hist_s[L_LEAVES + 256 + (lb >> 8)], 1);
  }
  __syncthreads();

  const int row = blockIdx.x * 256 + t;
  const int lab = labels[row];
  const int a2 = lab >> 4, a1 = lab >> 8;
  const int cEq = hist_s[lab] + 1;
  const int cS2 = hist_s[L_LEAVES + a2] + 17;
  const int cS1 = hist_s[L_LEAVES + 256 + a1] + 273;
  float ps0 = 0, ps1 = 0, ps2 = 0, ns0 = 0, ns1 = 0, ns2 = 0;
  const float* pp = partials + (size_t)row * NBX * 6;
  for (int b = 0; b < NBX; ++b) {
    ps0 += pp[b * 6 + 0];
    ps1 += pp[b * 6 + 1];
    ps2 += pp[b * 6 + 2];
    ns0 += pp[b * 6 + 3];
    ns1 += pp[b * 6 + 4];
    ns2 += pp[b * 6 + 5];
  }
  float ce = 0.f;
  {
    float pl = ps2 / fmaxf((float)cEq, 1e-6f);
    ce += logf(ns2 + (float)cEq + __expf(pl)) - pl;
  }
  {
    float pl = ps1 / fmaxf((float)(cS2 - cEq), 1e-6f);
    ce += logf(ns1 + (float)cS2 + __expf(pl)) - pl;
  }
  {
    float pl = ps0 / fmaxf((float)(cS1 - cS2), 1e-6f);
    ce += logf(ns0 + (float)cS1 + __expf(pl)) - pl;
  }
  float contrib = ce / depth[lab] * (3.0f / (float)N1);
  for (int off = 32; off > 0; off >>= 1) contrib += __shfl_down(contrib, off);
  __shared__ float wsum[4];
  const int lane = t & 63, wid = t >> 6;
  if (lane == 0) wsum[wid] = contrib;
  __syncthreads();
  if (t == 0) {
    const float tot = wsum[0] + wsum[1] + wsum[2] + wsum[3];
    atomicAdd(&out[0], tot);
    atomicAdd(&out[1], tot);
  }
}

// ---------------------------------------------------------------------------
extern "C" void kernel_launch(void* const* d_in, const int* in_sizes, int n_in,
                              void* d_out, int out_size, void* d_ws,
                              size_t ws_size, hipStream_t stream) {
  const float* q = (const float*)d_in[0];
  const float* vc = (const float*)d_in[1];
  const int* labels = (const int*)d_in[2];
  const float* depth = (const float*)d_in[6];
  float* out = (float*)d_out;

  unsigned char* kn = (unsigned char*)d_ws;  // N2P*DPROJ fp8 = 5.6 MB
  float* partials = (float*)((char*)d_ws + (size_t)N2P * DPROJ);
  // partials: N1 * NBX * 6 floats (~1.06 MB), fully written -> no memset

  normalize_kernel<<<N2P, 256, 0, stream>>>(q, vc, kn, out);

  dim3 grid(NBX, N1 / BM);
  gemm_loss_kernel<<<grid, 256, 0, stream>>>(kn, labels, partials);

  finalize_kernel<<<4, 256, 0, stream>>>(partials, labels, depth, out);
}

// Round 15
// 45.165 us; speedup vs baseline: 1.3194x; 1.0116x over previous
//
#include <hip/hip_runtime.h>
#include <math.h>

#define N1 1024
#define DPROJ 1024
#define M_NODES 4368
#define N2 (N1 + M_NODES)      // 5392
#define N2P 5504               // padded to 43*128 for the GEMM
#define L_LEAVES 4096
#define INV_T (1.0f / 0.07f)
#define NBX 43                 // N2P / BN

typedef float f32x4 __attribute__((ext_vector_type(4)));

// ---------------------------------------------------------------------------
// Kernel A: fused normalize + fp8(e4m3) cast. kn[row] = row/max(||row||,1e-12)
// quantized to OCP e4m3; rows >= N2 zero-filled. Block 0 also zeroes d_out.
// ---------------------------------------------------------------------------
__global__ __launch_bounds__(256) void normalize_kernel(
    const float* __restrict__ q, const float* __restrict__ vc,
    unsigned char* __restrict__ kn, float* __restrict__ out) {
  const int row = blockIdx.x;
  if (row == 0 && threadIdx.x == 0) { out[0] = 0.f; out[1] = 0.f; }
  int* dst = (int*)(kn + (size_t)row * DPROJ);
  if (row >= N2) {
    dst[threadIdx.x] = 0;
    return;
  }
  const float* src = (row < N1) ? q + (size_t)row * DPROJ
                                : vc + (size_t)(row - N1) * DPROJ;
  float4 v = ((const float4*)src)[threadIdx.x];
  float s = v.x * v.x + v.y * v.y + v.z * v.z + v.w * v.w;
  for (int off = 32; off > 0; off >>= 1) s += __shfl_down(s, off);
  __shared__ float wsum[4];
  const int lane = threadIdx.x & 63, wid = threadIdx.x >> 6;
  if (lane == 0) wsum[wid] = s;
  __syncthreads();
  const float tot = wsum[0] + wsum[1] + wsum[2] + wsum[3];
  const float inv = 1.0f / fmaxf(sqrtf(tot), 1e-12f);
  int p = __builtin_amdgcn_cvt_pk_fp8_f32(v.x * inv, v.y * inv, 0, false);
  p = __builtin_amdgcn_cvt_pk_fp8_f32(v.z * inv, v.w * inv, p, true);
  dst[threadIdx.x] = p;
}

// ---------------------------------------------------------------------------
// Kernel B: fused GEMM + loss partials — fp8, BK=128 (R15).
// R12 proved barrier-pair count dominates (BK 32->64 = -4.2us); fp8 makes
// BK=128 affordable: NT=8 barrier-pairs (was 16), tile rows = 128 B so the
// R12-verified byte-level swizzle carries over verbatim:
//   staging: one gload16 = 8 rows x 128 B; global granule pre-swizzled
//   (lane&7)^((lane>>3)&7); LDS linear.
//   reads: b64 at subslot s = kk*4+g (kk=0..3, g=lane>>4), physical
//   s ^ (2*(row&7)) — bit0 untouched -> write granules intact; row&7 =
//   lane&7 (fragment row bases are multiples of 16).
// Sync: R14's scheme — 2 bufs, STAGE(it+1) first, counted vmcnt(6) (own 6
// staging loads of tile it), raw s_barriers, chunked XCD swizzle.
// LDS 52 KB -> 3 blocks/CU; 688 blocks.
// ---------------------------------------------------------------------------
#define BM 64
#define BN 128
#define BK 128
#define NT (DPROJ / BK)

__device__ __forceinline__ void gload16(const unsigned char* g,
                                        unsigned char* l) {
  __builtin_amdgcn_global_load_lds(
      (const __attribute__((address_space(1))) void*)g,
      (__attribute__((address_space(3))) void*)l, 16, 0, 0);
}

__global__ __launch_bounds__(256, 3) void gemm_loss_kernel(
    const unsigned char* __restrict__ kn, const int* __restrict__ labels,
    float* __restrict__ partials) {
  __shared__ unsigned char As[2][BM][BK];   // 16 KB
  __shared__ unsigned char Bs[2][BN][BK];   // 32 KB
  __shared__ int lab_r[BM];                 // 256 B
  __shared__ int lab_c[BN];                 // 512 B
  __shared__ float blk_part[BM][2][6];      // 3 KB
  // Chunked bijective XCD swizzle (688 = 8 x 86), y-fastest chunks.
  const int wg = blockIdx.y * NBX + blockIdx.x;
  const int vid = (wg & 7) * 86 + (wg >> 3);
  const int bx = vid >> 4;          // 0..42
  const int by = vid & 15;          // 0..15
  const int j0 = bx * BN;
  const int i0 = by * BM;
  const int t = threadIdx.x;
  const int lane = t & 63, w = t >> 6;
  const int wm = w >> 1, wn = w & 1;   // wave grid 2x2, wave tile 32x64

  if (t < BM) lab_r[t] = labels[i0 + t];
  if (t < BN && j0 + t < N1) lab_c[t] = labels[j0 + t];

  f32x4 acc[2][4] = {};

  // Staging: one gload16 = 8 rows x 128 B. lane -> row = lane>>3, granule
  // = lane&7; global granule pre-swizzled by row&7: (lane&7)^((lane>>3)&7).
  const int rik = lane >> 3;
  const int gswz = ((lane & 7) ^ ((lane >> 3) & 7)) * 16;
  // Wave w: A rows [16w,16w+16) (2 gloads); B rows [32w,32w+32) (4 gloads).
  const unsigned char* gA0 = kn + (size_t)(i0 + w * 16 + rik) * DPROJ + gswz;
  const unsigned char* gA1 = gA0 + (size_t)8 * DPROJ;
  const unsigned char* gB0 = kn + (size_t)(j0 + w * 32 + rik) * DPROJ + gswz;
  const unsigned char* gB1 = gB0 + (size_t)8 * DPROJ;
  const unsigned char* gB2 = gB0 + (size_t)16 * DPROJ;
  const unsigned char* gB3 = gB0 + (size_t)24 * DPROJ;

  // Fragment reads: row = base + (lane&15), bases mult of 16 -> row&7 =
  // lane&7. Logical 8B-subslot s = kk*4 + g (g = lane>>4), physical =
  // s ^ (2*(lane&7)); byte offset = subslot*8.
  const int ar = wm * 32 + (lane & 15);
  const int br = wn * 64 + (lane & 15);
  const int x2 = 2 * (lane & 7);
  const int g4 = lane >> 4;

#define STAGE(buf, k0)                             \
  do {                                             \
    gload16(gA0 + (k0), &As[buf][w * 16][0]);      \
    gload16(gA1 + (k0), &As[buf][w * 16 + 8][0]);  \
    gload16(gB0 + (k0), &Bs[buf][w * 32][0]);      \
    gload16(gB1 + (k0), &Bs[buf][w * 32 + 8][0]);  \
    gload16(gB2 + (k0), &Bs[buf][w * 32 + 16][0]); \
    gload16(gB3 + (k0), &Bs[buf][w * 32 + 24][0]); \
  } while (0)

  // Prologue: tile 0 into buf 0; full drain (labels visible too).
  STAGE(0, 0);
  __syncthreads();

#pragma unroll 2
  for (int it = 0; it < NT; ++it) {
    const int cur = it & 1;
    if (it + 1 < NT) {
      STAGE(cur ^ 1, (it + 1) * BK);
      asm volatile("s_waitcnt vmcnt(6)" ::: "memory");  // oldest 6 = tile it
    } else {
      asm volatile("s_waitcnt vmcnt(0)" ::: "memory");
    }
    __builtin_amdgcn_s_barrier();   // all waves' tile-it loads complete

#pragma unroll
    for (int kk = 0; kk < 4; ++kk) {
      const int kf = ((kk * 4 + g4) ^ x2) * 8;
      long a0 = *(const long*)&As[cur][ar][kf];
      long a1 = *(const long*)&As[cur][ar + 16][kf];
      long b0 = *(const long*)&Bs[cur][br][kf];
      long b1 = *(const long*)&Bs[cur][br + 16][kf];
      long b2 = *(const long*)&Bs[cur][br + 32][kf];
      long b3 = *(const long*)&Bs[cur][br + 48][kf];
      acc[0][0] = __builtin_amdgcn_mfma_f32_16x16x32_fp8_fp8(a0, b0, acc[0][0], 0, 0, 0);
      acc[0][1] = __builtin_amdgcn_mfma_f32_16x16x32_fp8_fp8(a0, b1, acc[0][1], 0, 0, 0);
      acc[0][2] = __builtin_amdgcn_mfma_f32_16x16x32_fp8_fp8(a0, b2, acc[0][2], 0, 0, 0);
      acc[0][3] = __builtin_amdgcn_mfma_f32_16x16x32_fp8_fp8(a0, b3, acc[0][3], 0, 0, 0);
      acc[1][0] = __builtin_amdgcn_mfma_f32_16x16x32_fp8_fp8(a1, b0, acc[1][0], 0, 0, 0);
      acc[1][1] = __builtin_amdgcn_mfma_f32_16x16x32_fp8_fp8(a1, b1, acc[1][1], 0, 0, 0);
      acc[1][2] = __builtin_amdgcn_mfma_f32_16x16x32_fp8_fp8(a1, b2, acc[1][2], 0, 0, 0);
      acc[1][3] = __builtin_amdgcn_mfma_f32_16x16x32_fp8_fp8(a1, b3, acc[1][3], 0, 0, 0);
    }

    __builtin_amdgcn_s_barrier();   // reads of buf[cur] done -> reusable
  }

  // Fused epilogue. C/D layout: col=lane&15, row=(lane>>4)*4+j [m89,
  // dtype-independent per m121-m128].
  const int g = lane >> 4;
  const int p = lane & 15;
#pragma unroll
  for (int m = 0; m < 2; ++m) {
#pragma unroll
    for (int j = 0; j < 4; ++j) {
      const int rloc = wm * 32 + m * 16 + g * 4 + j;
      const int lab = lab_r[rloc];
      const int a2 = lab >> 4, a1 = lab >> 8;
      float ps0 = 0, ps1 = 0, ps2 = 0, ns0 = 0, ns1 = 0, ns2 = 0;
#pragma unroll
      for (int n = 0; n < 4; ++n) {
        const int cloc = wn * 64 + n * 16 + p;
        const int gc = j0 + cloc;
        if (gc < N2) {
          const int nid = (gc < N1) ? lab_c[cloc] : (gc - N1);
          const bool isLeaf = nid < L_LEAVES;
          const bool isD2 = (nid >= L_LEAVES) && (nid < L_LEAVES + 256);
          const bool eq = (nid == lab);
          const bool inS2 =
              (nid == L_LEAVES + a2) || (isLeaf && ((nid >> 4) == a2));
          const bool inS1 = (nid == L_LEAVES + 256 + a1) ||
                            (isD2 && (((nid - L_LEAVES) >> 4) == a1)) ||
                            (isLeaf && ((nid >> 8) == a1));
          const float v = acc[m][n][j] * INV_T;
          const float e = __expf(v);
          if (eq) ps2 += v; else ns2 += e;
          if (inS2) { if (!eq) ps1 += v; } else ns1 += e;
          if (inS1) { if (!inS2) ps0 += v; } else ns0 += e;
        }
      }
#pragma unroll
      for (int msk = 1; msk < 16; msk <<= 1) {
        ps0 += __shfl_xor(ps0, msk);
        ps1 += __shfl_xor(ps1, msk);
        ps2 += __shfl_xor(ps2, msk);
        ns0 += __shfl_xor(ns0, msk);
        ns1 += __shfl_xor(ns1, msk);
        ns2 += __shfl_xor(ns2, msk);
      }
      if (p == 0) {
        float* d = &blk_part[rloc][wn][0];
        d[0] = ps0; d[1] = ps1; d[2] = ps2;
        d[3] = ns0; d[4] = ns1; d[5] = ns2;
      }
    }
  }
  __syncthreads();
  for (int idx = t; idx < BM * 6; idx += 256) {
    const int r = idx / 6, k = idx % 6;
    const float val = blk_part[r][0][k] + blk_part[r][1][k];
    partials[((size_t)(i0 + r) * NBX + bx) * 6 + k] = val;
  }
}

// ---------------------------------------------------------------------------
// Kernel C: finalize. LDS label histogram, sum 43 slices/row, CE with
// analytic counts: |eq|=hist[lab]+1; |S2|=hist2+17; |S1|=hist1+273.
// Masked entries contribute exp(0)=1 -> +|set| in the LSE.
// ---------------------------------------------------------------------------
__global__ __launch_bounds__(256) void finalize_kernel(
    const float* __restrict__ partials, const int* __restrict__ labels,
    const float* __restrict__ depth, float* __restrict__ out) {
  __shared__ int hist_s[M_NODES];   // 17.4 KB
  const int t = threadIdx.x;
  for (int i = t; i < M_NODES; i += 256) hist_s[i] = 0;
  __syncthreads();
  for (int i = t; i < N1; i += 256) {
    const int lb = labels[i];
    atomicAdd(&hist_s[lb], 1);
    atomicAdd(&hist_s[L_LEAVES + (lb >> 4)], 1);
    atomicAdd(&hist_s[L_LEAVES + 256 + (lb >> 8)], 1);
  }
  __syncthreads();

  const int row = blockIdx.x * 256 + t;
  const int lab = labels[row];
  const int a2 = lab >> 4, a1 = lab >> 8;
  const int cEq = hist_s[lab] + 1;
  const int cS2 = hist_s[L_LEAVES + a2] + 17;
  const int cS1 = hist_s[L_LEAVES + 256 + a1] + 273;
  float ps0 = 0, ps1 = 0, ps2 = 0, ns0 = 0, ns1 = 0, ns2 = 0;
  const float* pp = partials + (size_t)row * NBX * 6;
  for (int b = 0; b < NBX; ++b) {
    ps0 += pp[b * 6 + 0];
    ps1 += pp[b * 6 + 1];
    ps2 += pp[b * 6 + 2];
    ns0 += pp[b * 6 + 3];
    ns1 += pp[b * 6 + 4];
    ns2 += pp[b * 6 + 5];
  }
  float ce = 0.f;
  {
    float pl = ps2 / fmaxf((float)cEq, 1e-6f);
    ce += logf(ns2 + (float)cEq + __expf(pl)) - pl;
  }
  {
    float pl = ps1 / fmaxf((float)(cS2 - cEq), 1e-6f);
    ce += logf(ns1 + (float)cS2 + __expf(pl)) - pl;
  }
  {
    float pl = ps0 / fmaxf((float)(cS1 - cS2), 1e-6f);
    ce += logf(ns0 + (float)cS1 + __expf(pl)) - pl;
  }
  float contrib = ce / depth[lab] * (3.0f / (float)N1);
  for (int off = 32; off > 0; off >>= 1) contrib += __shfl_down(contrib, off);
  __shared__ float wsum[4];
  const int lane = t & 63, wid = t >> 6;
  if (lane == 0) wsum[wid] = contrib;
  __syncthreads();
  if (t == 0) {
    const float tot = wsum[0] + wsum[1] + wsum[2] + wsum[3];
    atomicAdd(&out[0], tot);
    atomicAdd(&out[1], tot);
  }
}

// ---------------------------------------------------------------------------
extern "C" void kernel_launch(void* const* d_in, const int* in_sizes, int n_in,
                              void* d_out, int out_size, void* d_ws,
                              size_t ws_size, hipStream_t stream) {
  const float* q = (const float*)d_in[0];
  const float* vc = (const float*)d_in[1];
  const int* labels = (const int*)d_in[2];
  const float* depth = (const float*)d_in[6];
  float* out = (float*)d_out;

  unsigned char* kn = (unsigned char*)d_ws;  // N2P*DPROJ fp8 = 5.6 MB
  float* partials = (float*)((char*)d_ws + (size_t)N2P * DPROJ);
  // partials: N1 * NBX * 6 floats (~1.06 MB), fully written -> no memset

  normalize_kernel<<<N2P, 256, 0, stream>>>(q, vc, kn, out);

  dim3 grid(NBX, N1 / BM);
  gemm_loss_kernel<<<grid, 256, 0, stream>>>(kn, labels, partials);

  finalize_kernel<<<4, 256, 0, stream>>>(partials, labels, depth, out);
}

// Round 17
// 40.947 us; speedup vs baseline: 1.4553x; 1.1030x over previous
//
#include <hip/hip_runtime.h>
#include <math.h>

#define N1 1024
#define DPROJ 1024
#define M_NODES 4368
#define N2 (N1 + M_NODES)      // 5392
#define N2P 5504               // padded to 43*128 for the GEMM
#define L_LEAVES 4096
#define INV_T (1.0f / 0.07f)
#define NBX 43                 // N2P / BN

typedef float f32x4 __attribute__((ext_vector_type(4)));

// ---------------------------------------------------------------------------
// DPP 16-lane sum reduction — VALU pipe only (no LDS ops).
// v_add_f32 + row_ror rotations within each 16-lane row: after ror
// 1,2,4,8 every lane holds the row total. Replaces 4x shfl_xor
// (ds_swizzle, LDS pipe) per value. R16 fix: DPP ctrl must be a
// compile-time constant -> template parameter.
// ---------------------------------------------------------------------------
template <int CTRL>
__device__ __forceinline__ float dpp_ror_add(float x) {
  int r = __builtin_amdgcn_update_dpp(0, __float_as_int(x), CTRL, 0xF, 0xF,
                                      true);
  return x + __int_as_float(r);
}
__device__ __forceinline__ float rowsum16(float x) {
  x = dpp_ror_add<0x121>(x);   // row_ror:1
  x = dpp_ror_add<0x122>(x);   // row_ror:2
  x = dpp_ror_add<0x124>(x);   // row_ror:4
  x = dpp_ror_add<0x128>(x);   // row_ror:8
  return x;
}

// ---------------------------------------------------------------------------
// Kernel A: fused normalize + fp8(e4m3) cast. kn[row] = row/max(||row||,1e-12)
// quantized to OCP e4m3; rows >= N2 zero-filled. Block 0 also zeroes d_out.
// ---------------------------------------------------------------------------
__global__ __launch_bounds__(256) void normalize_kernel(
    const float* __restrict__ q, const float* __restrict__ vc,
    unsigned char* __restrict__ kn, float* __restrict__ out) {
  const int row = blockIdx.x;
  if (row == 0 && threadIdx.x == 0) { out[0] = 0.f; out[1] = 0.f; }
  int* dst = (int*)(kn + (size_t)row * DPROJ);
  if (row >= N2) {
    dst[threadIdx.x] = 0;
    return;
  }
  const float* src = (row < N1) ? q + (size_t)row * DPROJ
                                : vc + (size_t)(row - N1) * DPROJ;
  float4 v = ((const float4*)src)[threadIdx.x];
  float s = v.x * v.x + v.y * v.y + v.z * v.z + v.w * v.w;
  for (int off = 32; off > 0; off >>= 1) s += __shfl_down(s, off);
  __shared__ float wsum[4];
  const int lane = threadIdx.x & 63, wid = threadIdx.x >> 6;
  if (lane == 0) wsum[wid] = s;
  __syncthreads();
  const float tot = wsum[0] + wsum[1] + wsum[2] + wsum[3];
  const float inv = 1.0f / fmaxf(sqrtf(tot), 1e-12f);
  int p = __builtin_amdgcn_cvt_pk_fp8_f32(v.x * inv, v.y * inv, 0, false);
  p = __builtin_amdgcn_cvt_pk_fp8_f32(v.z * inv, v.w * inv, p, true);
  dst[threadIdx.x] = p;
}

// ---------------------------------------------------------------------------
// Kernel B: fused GEMM + loss partials — fp8, BK=128 (R15 structure).
// R16/R17 changes (epilogue-focused; main loop identical except setprio):
//  (1) 16-lane reductions via DPP row_ror adds (VALU) instead of 192
//      ds_swizzle shuffles per thread — epilogue was ~5us of LDS-pipe
//      time (~12K cyc/CU), larger than the main loop's ds_read budget.
//  (2) per-column tree classification hoisted out of the 8-row loop
//      (columns identical across (m,j)).
//  (3) T5 s_setprio(1) around the MFMA cluster (3 independent blocks/CU).
// ---------------------------------------------------------------------------
#define BM 64
#define BN 128
#define BK 128
#define NT (DPROJ / BK)

__device__ __forceinline__ void gload16(const unsigned char* g,
                                        unsigned char* l) {
  __builtin_amdgcn_global_load_lds(
      (const __attribute__((address_space(1))) void*)g,
      (__attribute__((address_space(3))) void*)l, 16, 0, 0);
}

__global__ __launch_bounds__(256, 3) void gemm_loss_kernel(
    const unsigned char* __restrict__ kn, const int* __restrict__ labels,
    float* __restrict__ partials) {
  __shared__ unsigned char As[2][BM][BK];   // 16 KB
  __shared__ unsigned char Bs[2][BN][BK];   // 32 KB
  __shared__ int lab_r[BM];                 // 256 B
  __shared__ int lab_c[BN];                 // 512 B
  __shared__ float blk_part[BM][2][6];      // 3 KB
  // Chunked bijective XCD swizzle (688 = 8 x 86), y-fastest chunks.
  const int wg = blockIdx.y * NBX + blockIdx.x;
  const int vid = (wg & 7) * 86 + (wg >> 3);
  const int bx = vid >> 4;          // 0..42
  const int by = vid & 15;          // 0..15
  const int j0 = bx * BN;
  const int i0 = by * BM;
  const int t = threadIdx.x;
  const int lane = t & 63, w = t >> 6;
  const int wm = w >> 1, wn = w & 1;   // wave grid 2x2, wave tile 32x64

  if (t < BM) lab_r[t] = labels[i0 + t];
  if (t < BN && j0 + t < N1) lab_c[t] = labels[j0 + t];

  f32x4 acc[2][4] = {};

  // Staging: one gload16 = 8 rows x 128 B. lane -> row = lane>>3, granule
  // = lane&7; global granule pre-swizzled by row&7: (lane&7)^((lane>>3)&7).
  const int rik = lane >> 3;
  const int gswz = ((lane & 7) ^ ((lane >> 3) & 7)) * 16;
  // Wave w: A rows [16w,16w+16) (2 gloads); B rows [32w,32w+32) (4 gloads).
  const unsigned char* gA0 = kn + (size_t)(i0 + w * 16 + rik) * DPROJ + gswz;
  const unsigned char* gA1 = gA0 + (size_t)8 * DPROJ;
  const unsigned char* gB0 = kn + (size_t)(j0 + w * 32 + rik) * DPROJ + gswz;
  const unsigned char* gB1 = gB0 + (size_t)8 * DPROJ;
  const unsigned char* gB2 = gB0 + (size_t)16 * DPROJ;
  const unsigned char* gB3 = gB0 + (size_t)24 * DPROJ;

  // Fragment reads: row = base + (lane&15), bases mult of 16 -> row&7 =
  // lane&7. Logical 8B-subslot s = kk*4 + g (g = lane>>4), physical =
  // s ^ (2*(lane&7)); byte offset = subslot*8.
  const int ar = wm * 32 + (lane & 15);
  const int br = wn * 64 + (lane & 15);
  const int x2 = 2 * (lane & 7);
  const int g4 = lane >> 4;

#define STAGE(buf, k0)                             \
  do {                                             \
    gload16(gA0 + (k0), &As[buf][w * 16][0]);      \
    gload16(gA1 + (k0), &As[buf][w * 16 + 8][0]);  \
    gload16(gB0 + (k0), &Bs[buf][w * 32][0]);      \
    gload16(gB1 + (k0), &Bs[buf][w * 32 + 8][0]);  \
    gload16(gB2 + (k0), &Bs[buf][w * 32 + 16][0]); \
    gload16(gB3 + (k0), &Bs[buf][w * 32 + 24][0]); \
  } while (0)

  // Prologue: tile 0 into buf 0; full drain (labels visible too).
  STAGE(0, 0);
  __syncthreads();

#pragma unroll 2
  for (int it = 0; it < NT; ++it) {
    const int cur = it & 1;
    if (it + 1 < NT) {
      STAGE(cur ^ 1, (it + 1) * BK);
      asm volatile("s_waitcnt vmcnt(6)" ::: "memory");  // oldest 6 = tile it
    } else {
      asm volatile("s_waitcnt vmcnt(0)" ::: "memory");
    }
    __builtin_amdgcn_s_barrier();   // all waves' tile-it loads complete

    __builtin_amdgcn_s_setprio(1);
#pragma unroll
    for (int kk = 0; kk < 4; ++kk) {
      const int kf = ((kk * 4 + g4) ^ x2) * 8;
      long a0 = *(const long*)&As[cur][ar][kf];
      long a1 = *(const long*)&As[cur][ar + 16][kf];
      long b0 = *(const long*)&Bs[cur][br][kf];
      long b1 = *(const long*)&Bs[cur][br + 16][kf];
      long b2 = *(const long*)&Bs[cur][br + 32][kf];
      long b3 = *(const long*)&Bs[cur][br + 48][kf];
      acc[0][0] = __builtin_amdgcn_mfma_f32_16x16x32_fp8_fp8(a0, b0, acc[0][0], 0, 0, 0);
      acc[0][1] = __builtin_amdgcn_mfma_f32_16x16x32_fp8_fp8(a0, b1, acc[0][1], 0, 0, 0);
      acc[0][2] = __builtin_amdgcn_mfma_f32_16x16x32_fp8_fp8(a0, b2, acc[0][2], 0, 0, 0);
      acc[0][3] = __builtin_amdgcn_mfma_f32_16x16x32_fp8_fp8(a0, b3, acc[0][3], 0, 0, 0);
      acc[1][0] = __builtin_amdgcn_mfma_f32_16x16x32_fp8_fp8(a1, b0, acc[1][0], 0, 0, 0);
      acc[1][1] = __builtin_amdgcn_mfma_f32_16x16x32_fp8_fp8(a1, b1, acc[1][1], 0, 0, 0);
      acc[1][2] = __builtin_amdgcn_mfma_f32_16x16x32_fp8_fp8(a1, b2, acc[1][2], 0, 0, 0);
      acc[1][3] = __builtin_amdgcn_mfma_f32_16x16x32_fp8_fp8(a1, b3, acc[1][3], 0, 0, 0);
    }
    __builtin_amdgcn_s_setprio(0);

    __builtin_amdgcn_s_barrier();   // reads of buf[cur] done -> reusable
  }

  // Fused epilogue. C/D layout: col=lane&15, row=(lane>>4)*4+j [m89,
  // dtype-independent per m121-m128].
  const int g = lane >> 4;
  const int p = lane & 15;

  // Per-column classification (identical across the 8 row-instances).
  int nid_c[4];
  bool val_c[4], leaf_c[4], d2_c[4];
  int n4_c[4], n8_c[4], d2p_c[4];
#pragma unroll
  for (int n = 0; n < 4; ++n) {
    const int cloc = wn * 64 + n * 16 + p;
    const int gc = j0 + cloc;
    val_c[n] = (gc < N2);
    const int nid = (gc < N1) ? lab_c[cloc] : (gc - N1);
    nid_c[n] = nid;
    leaf_c[n] = nid < L_LEAVES;
    d2_c[n] = (nid >= L_LEAVES) && (nid < L_LEAVES + 256);
    n4_c[n] = nid >> 4;
    n8_c[n] = nid >> 8;
    d2p_c[n] = (nid - L_LEAVES) >> 4;
  }

#pragma unroll
  for (int m = 0; m < 2; ++m) {
#pragma unroll
    for (int j = 0; j < 4; ++j) {
      const int rloc = wm * 32 + m * 16 + g * 4 + j;
      const int lab = lab_r[rloc];
      const int a2 = lab >> 4, a1 = lab >> 8;
      float ps0 = 0, ps1 = 0, ps2 = 0, ns0 = 0, ns1 = 0, ns2 = 0;
#pragma unroll
      for (int n = 0; n < 4; ++n) {
        if (val_c[n]) {
          const int nid = nid_c[n];
          const bool eq = (nid == lab);
          const bool inS2 =
              (nid == L_LEAVES + a2) || (leaf_c[n] && (n4_c[n] == a2));
          const bool inS1 = (nid == L_LEAVES + 256 + a1) ||
                            (d2_c[n] && (d2p_c[n] == a1)) ||
                            (leaf_c[n] && (n8_c[n] == a1));
          const float v = acc[m][n][j] * INV_T;
          const float e = __expf(v);
          if (eq) ps2 += v; else ns2 += e;
          if (inS2) { if (!eq) ps1 += v; } else ns1 += e;
          if (inS1) { if (!inS2) ps0 += v; } else ns0 += e;
        }
      }
      // VALU-only 16-lane reductions (DPP row_ror).
      ps0 = rowsum16(ps0);
      ps1 = rowsum16(ps1);
      ps2 = rowsum16(ps2);
      ns0 = rowsum16(ns0);
      ns1 = rowsum16(ns1);
      ns2 = rowsum16(ns2);
      if (p == 0) {
        float* d = &blk_part[rloc][wn][0];
        d[0] = ps0; d[1] = ps1; d[2] = ps2;
        d[3] = ns0; d[4] = ns1; d[5] = ns2;
      }
    }
  }
  __syncthreads();
  for (int idx = t; idx < BM * 6; idx += 256) {
    const int r = idx / 6, k = idx % 6;
    const float val = blk_part[r][0][k] + blk_part[r][1][k];
    partials[((size_t)(i0 + r) * NBX + bx) * 6 + k] = val;
  }
}

// ---------------------------------------------------------------------------
// Kernel C: finalize. LDS label histogram, sum 43 slices/row, CE with
// analytic counts: |eq|=hist[lab]+1; |S2|=hist2+17; |S1|=hist1+273.
// Masked entries contribute exp(0)=1 -> +|set| in the LSE.
// ---------------------------------------------------------------------------
__global__ __launch_bounds__(256) void finalize_kernel(
    const float* __restrict__ partials, const int* __restrict__ labels,
    const float* __restrict__ depth, float* __restrict__ out) {
  __shared__ int hist_s[M_NODES];   // 17.4 KB
  const int t = threadIdx.x;
  for (int i = t; i < M_NODES; i += 256) hist_s[i] = 0;
  __syncthreads();
  for (int i = t; i < N1; i += 256) {
    const int lb = labels[i];
    atomicAdd(&hist_s[lb], 1);
    atomicAdd(&hist_s[L_LEAVES + (lb >> 4)], 1);
    atomicAdd(&hist_s[L_LEAVES + 256 + (lb >> 8)], 1);
  }
  __syncthreads();

  const int row = blockIdx.x * 256 + t;
  const int lab = labels[row];
  const int a2 = lab >> 4, a1 = lab >> 8;
  const int cEq = hist_s[lab] + 1;
  const int cS2 = hist_s[L_LEAVES + a2] + 17;
  const int cS1 = hist_s[L_LEAVES + 256 + a1] + 273;
  float ps0 = 0, ps1 = 0, ps2 = 0, ns0 = 0, ns1 = 0, ns2 = 0;
  const float* pp = partials + (size_t)row * NBX * 6;
  for (int b = 0; b < NBX; ++b) {
    ps0 += pp[b * 6 + 0];
    ps1 += pp[b * 6 + 1];
    ps2 += pp[b * 6 + 2];
    ns0 += pp[b * 6 + 3];
    ns1 += pp[b * 6 + 4];
    ns2 += pp[b * 6 + 5];
  }
  float ce = 0.f;
  {
    float pl = ps2 / fmaxf((float)cEq, 1e-6f);
    ce += logf(ns2 + (float)cEq + __expf(pl)) - pl;
  }
  {
    float pl = ps1 / fmaxf((float)(cS2 - cEq), 1e-6f);
    ce += logf(ns1 + (float)cS2 + __expf(pl)) - pl;
  }
  {
    float pl = ps0 / fmaxf((float)(cS1 - cS2), 1e-6f);
    ce += logf(ns0 + (float)cS1 + __expf(pl)) - pl;
  }
  float contrib = ce / depth[lab] * (3.0f / (float)N1);
  for (int off = 32; off > 0; off >>= 1) contrib += __shfl_down(contrib, off);
  __shared__ float wsum[4];
  const int lane = t & 63, wid = t >> 6;
  if (lane == 0) wsum[wid] = contrib;
  __syncthreads();
  if (t == 0) {
    const float tot = wsum[0] + wsum[1] + wsum[2] + wsum[3];
    atomicAdd(&out[0], tot);
    atomicAdd(&out[1], tot);
  }
}

// ---------------------------------------------------------------------------
extern "C" void kernel_launch(void* const* d_in, const int* in_sizes, int n_in,
                              void* d_out, int out_size, void* d_ws,
                              size_t ws_size, hipStream_t stream) {
  const float* q = (const float*)d_in[0];
  const float* vc = (const float*)d_in[1];
  const int* labels = (const int*)d_in[2];
  const float* depth = (const float*)d_in[6];
  float* out = (float*)d_out;

  unsigned char* kn = (unsigned char*)d_ws;  // N2P*DPROJ fp8 = 5.6 MB
  float* partials = (float*)((char*)d_ws + (size_t)N2P * DPROJ);
  // partials: N1 * NBX * 6 floats (~1.06 MB), fully written -> no memset

  normalize_kernel<<<N2P, 256, 0, stream>>>(q, vc, kn, out);

  dim3 grid(NBX, N1 / BM);
  gemm_loss_kernel<<<grid, 256, 0, stream>>>(kn, labels, partials);

  finalize_kernel<<<4, 256, 0, stream>>>(partials, labels, depth, out);
}